// Round 7
// baseline (302.649 us; speedup 1.0000x reference)
//
#include <hip/hip_runtime.h>

// CausalSelfAttention: B=4, T=2048, C=1024, H=16, D=64
// Pipeline: cvt(x,w) -> qkv GEMM (dbuf, XCD-chunked, swizzled LDS, V written transposed)
//           -> flash attn (swapped 32x32, KVBLK=128, fused dual-tile sweep, defer-max, dbuf)
//           -> proj GEMM

typedef unsigned short u16b;
typedef __bf16 bf16x8 __attribute__((ext_vector_type(8)));
typedef float f32x4 __attribute__((ext_vector_type(4)));
typedef float f32x16 __attribute__((ext_vector_type(16)));
typedef unsigned short u16x4 __attribute__((ext_vector_type(4)));

#define AS1(p) ((const __attribute__((address_space(1))) void*)(p))
#define AS3(p) ((__attribute__((address_space(3))) void*)(p))
#define GLDS(g, l) __builtin_amdgcn_global_load_lds(AS1(g), AS3(l), 16, 0, 0)

__device__ __forceinline__ u16b bfr(float v) {  // f32 -> bf16 bits, RNE
  union { float f; unsigned u; } x; x.f = v;
  unsigned r = x.u + 0x7fffu + ((x.u >> 16) & 1u);
  return (u16b)(r >> 16);
}

__device__ __forceinline__ unsigned pk2(float lo, float hi) {  // pack 2 f32 -> 2 bf16 in u32
  union { __bf16 h[2]; unsigned u; } t;
  t.h[0] = (__bf16)lo; t.h[1] = (__bf16)hi;
  return t.u;
}

union WB { unsigned u[4]; bf16x8 v; };

template <int O>
__device__ __forceinline__ WB packh(const f32x16& s) {  // 8 f32 -> bf16 B-frag (T12)
  unsigned a0 = pk2(s[O + 0], s[O + 1]), a1 = pk2(s[O + 2], s[O + 3]);
  unsigned b0 = pk2(s[O + 4], s[O + 5]), b1 = pk2(s[O + 6], s[O + 7]);
  auto r0 = __builtin_amdgcn_permlane32_swap(a0, b0, false, false);
  auto r1 = __builtin_amdgcn_permlane32_swap(a1, b1, false, false);
  unsigned o0[2], o1[2];
  __builtin_memcpy(o0, &r0, 8); __builtin_memcpy(o1, &r1, 8);
  WB w; w.u[0] = o0[0]; w.u[2] = o0[1]; w.u[1] = o1[0]; w.u[3] = o1[1];
  return w;
}

__device__ __forceinline__ float max16(const f32x16& v) {
  float a0 = fmaxf(v[0], v[1]), a1 = fmaxf(v[2], v[3]);
  float a2 = fmaxf(v[4], v[5]), a3 = fmaxf(v[6], v[7]);
  float b0 = fmaxf(v[8], v[9]), b1 = fmaxf(v[10], v[11]);
  float b2 = fmaxf(v[12], v[13]), b3 = fmaxf(v[14], v[15]);
  float c0 = fmaxf(a0, a1), c1 = fmaxf(a2, a3);
  float c2 = fmaxf(b0, b1), c3 = fmaxf(b2, b3);
  return fmaxf(fmaxf(c0, c1), fmaxf(c2, c3));
}

__device__ __forceinline__ float sum16(const f32x16& v) {
  float a0 = v[0] + v[1], a1 = v[2] + v[3], a2 = v[4] + v[5], a3 = v[6] + v[7];
  float b0 = v[8] + v[9], b1 = v[10] + v[11], b2 = v[12] + v[13], b3 = v[14] + v[15];
  float c0 = a0 + a1, c1 = a2 + a3, c2 = b0 + b1, c3 = b2 + b3;
  return (c0 + c1) + (c2 + c3);
}

// ---------------- x (fp32) -> bf16, vectorized ----------------
__global__ __launch_bounds__(256) void cvt_bf16_kernel(
    const float* __restrict__ src, u16b* __restrict__ dst, int n4) {
  int i = blockIdx.x * 256 + threadIdx.x;
  const int stride = gridDim.x * 256;
  for (; i < n4; i += stride) {
    const float4 v = reinterpret_cast<const float4*>(src)[i];
    u16x4 o;
    o[0] = bfr(v.x); o[1] = bfr(v.y); o[2] = bfr(v.z); o[3] = bfr(v.w);
    reinterpret_cast<u16x4*>(dst)[i] = o;
  }
}

// ---------------- weights: src[R][C] fp32 -> dst[C][R] bf16 (transpose) ----------------
__global__ __launch_bounds__(256) void transpose_cvt_kernel(
    const float* __restrict__ src, u16b* __restrict__ dst, int R, int C) {
  __shared__ u16b tile[64][72];
  const int nc = C >> 6;
  const int br = blockIdx.x / nc, bc = blockIdx.x % nc;
  const int r0 = br << 6, c0 = bc << 6;
  const int c = threadIdx.x & 63, r4 = threadIdx.x >> 6;
  #pragma unroll
  for (int i = 0; i < 16; ++i) {
    const int r = r4 + 4 * i;
    tile[r][c] = bfr(src[(size_t)(r0 + r) * C + c0 + c]);
  }
  __syncthreads();
  #pragma unroll
  for (int i = 0; i < 16; ++i) {
    const int rr = r4 + 4 * i;
    dst[(size_t)(c0 + rr) * R + r0 + c] = tile[c][rr];
  }
}

// ---------------- 128x128 tile bf16 GEMM: dbuf + XCD chunking + T2 swizzle ----------------
// LDS A/B tiles: [128 rows][64 B], physical 16B-chunk = logical ^ ((row>>1)&3).
// Staged with linear GLDS dest + pre-swizzled SOURCE chunk (rule #21).
// EPI==0: Q(scaled)/K as [B,H,T,D] bf16; V written TRANSPOSED as Vt [bh][64 d][2048 t]
// EPI==1: fp32 out [M][N]
template <int EPI>
__global__ __launch_bounds__(256, 2) void gemm128_kernel(
    const u16b* __restrict__ A, const u16b* __restrict__ Bt,
    const float* __restrict__ bias,
    u16b* __restrict__ oQ, u16b* __restrict__ oK, u16b* __restrict__ oVt,
    float* __restrict__ oF, int M, int N, int K) {
  __shared__ u16b smem[16384];  // 2 buf x (As 8KB + Bs 8KB); epilogue reuses all 32KB
  const int tid = threadIdx.x;
  const int wid = tid >> 6, lane = tid & 63;
  const int nb = N >> 7;
  const int lin = (blockIdx.x & 7) * ((int)gridDim.x >> 3) + (blockIdx.x >> 3);
  const int brow = lin / nb, bcol = lin % nb;
  const int wr = (wid >> 1) << 6, wc = (wid & 1) << 6;

  f32x4 acc[4][4] = {};

  const int ar = (wid << 4) + (lane >> 2);
  // source chunk pre-swizzle: logical chunk (lane&3) lands at phys (lane&3); must carry
  // global chunk (lane&3)^((row>>1)&3) = (lane&3)^((lane>>3)&3)
  const int acs = (((lane & 3) ^ ((lane >> 3) & 3))) << 3;
  const u16b* Ab = A + (size_t)((brow << 7) + ar) * K + acs;
  const u16b* Bb = Bt + (size_t)((bcol << 7) + ar) * K + acs;
  const int fr = lane & 15;
  const int pcs = (((lane >> 4) ^ ((fr >> 1) & 3))) << 4;  // phys chunk byte off for reads
  const int nk = K >> 5;

#define STAGE(bufi, kk)                                                        \
  {                                                                            \
    char* sb = (char*)smem + (bufi) * 16384;                                   \
    GLDS(Ab + (kk),                  sb + wid * 1024);                         \
    GLDS(Ab + (size_t)64 * K + (kk), sb + 4096 + wid * 1024);                  \
    GLDS(Bb + (kk),                  sb + 8192 + wid * 1024);                  \
    GLDS(Bb + (size_t)64 * K + (kk), sb + 12288 + wid * 1024);                 \
  }

  STAGE(0, 0);
  STAGE(1, 32);

  #pragma unroll 1
  for (int kt = 0; kt < nk; ++kt) {
    if (kt + 1 < nk) asm volatile("s_waitcnt vmcnt(4)" ::: "memory");
    else             asm volatile("s_waitcnt vmcnt(0)" ::: "memory");
    __builtin_amdgcn_s_barrier();

    const char* As = (const char*)smem + (kt & 1) * 16384;
    const char* Bs = As + 8192;
    bf16x8 af[4], bfv[4];
    #pragma unroll
    for (int i = 0; i < 4; ++i)
      af[i] = *(const bf16x8*)(As + (wr + i * 16 + fr) * 64 + pcs);
    #pragma unroll
    for (int j = 0; j < 4; ++j)
      bfv[j] = *(const bf16x8*)(Bs + (wc + j * 16 + fr) * 64 + pcs);
    __builtin_amdgcn_s_setprio(1);
    #pragma unroll
    for (int i = 0; i < 4; ++i)
      #pragma unroll
      for (int j = 0; j < 4; ++j)
        acc[i][j] = __builtin_amdgcn_mfma_f32_16x16x32_bf16(af[i], bfv[j], acc[i][j], 0, 0, 0);
    __builtin_amdgcn_s_setprio(0);

    __builtin_amdgcn_s_barrier();
    if (kt + 2 < nk) STAGE(kt & 1, (kt + 2) << 5);
  }
#undef STAGE

  const int fq = lane >> 4;
  if (EPI == 1) {
    #pragma unroll
    for (int j = 0; j < 4; ++j) {
      const int n0 = (bcol << 7) + wc + j * 16 + fr;
      const float bv = bias[n0];
      #pragma unroll
      for (int i = 0; i < 4; ++i) {
        #pragma unroll
        for (int r = 0; r < 4; ++r) {
          const int m0 = (brow << 7) + wr + i * 16 + fq * 4 + r;
          oF[(size_t)m0 * N + n0] = acc[i][j][r] + bv;
        }
      }
    }
  } else {
    const int sect = bcol >> 3;  // 0:Q 1:K 2:V (block-uniform)
    if (sect < 2) {
      const float qs = (sect == 0) ? 0.1803368801f : 1.0f;  // 1/sqrt(64)*log2(e) in Q
      u16b* oPtr = (sect == 0) ? oQ : oK;
      u16b* tile = (u16b*)smem;
      #pragma unroll
      for (int j = 0; j < 4; ++j) {
        const int n = wc + j * 16 + fr;
        const float bv = bias[(bcol << 7) + n];
        #pragma unroll
        for (int i = 0; i < 4; ++i) {
          #pragma unroll
          for (int r = 0; r < 4; ++r) {
            const int m = wr + i * 16 + fq * 4 + r;
            const int byteoff = m * 256 + (((n >> 3) ^ (m & 7)) << 4) + ((n & 7) << 1);
            *(u16b*)((char*)tile + byteoff) = bfr((acc[i][j][r] + bv) * qs);
          }
        }
      }
      __syncthreads();
      const int nh = wid >> 1;
      const int c = lane & 7;
      #pragma unroll
      for (int it = 0; it < 8; ++it) {
        const int m = ((wid & 1) << 6) + (it << 3) + (lane >> 3);
        const int chunk = (nh << 3) + (c ^ (m & 7));
        const bf16x8 val = *(const bf16x8*)((const char*)tile + m * 256 + chunk * 16);
        const int m0 = (brow << 7) + m;
        const int n0 = (bcol << 7) + (nh << 6) + (c << 3);
        const int bb = m0 >> 11, tt = m0 & 2047;
        const int h = (n0 >> 6) & 15, d = n0 & 63;
        *(bf16x8*)(oPtr + (((size_t)(bb * 16 + h) * 2048 + tt) * 64 + d)) = val;
      }
    } else {
      // V: LDS tile TRANSPOSED [nl 128][m 128] swizzled, store Vt[bh][d][t] rows
      u16b* tile = (u16b*)smem;
      #pragma unroll
      for (int j = 0; j < 4; ++j) {
        const int nl = wc + j * 16 + fr;
        const float bv = bias[(bcol << 7) + nl];
        #pragma unroll
        for (int i = 0; i < 4; ++i) {
          #pragma unroll
          for (int r = 0; r < 4; ++r) {
            const int m = wr + i * 16 + fq * 4 + r;
            const int byteoff = nl * 256 + (((m >> 3) ^ (nl & 7)) << 4) + ((m & 7) << 1);
            *(u16b*)((char*)tile + byteoff) = bfr(acc[i][j][r] + bv);
          }
        }
      }
      __syncthreads();
      const int row0 = wid << 5;
      const int c16 = lane & 15;
      const int rr = lane >> 4;
      const int t0 = (brow << 7) & 2047;
      const int bb = brow >> 4;
      #pragma unroll
      for (int it = 0; it < 8; ++it) {
        const int nl = row0 + (it << 2) + rr;
        const int pch = c16 ^ (nl & 7);
        const bf16x8 val = *(const bf16x8*)((const char*)tile + nl * 256 + pch * 16);
        const int h = ((bcol & 7) << 1) + (nl >> 6);
        const int d = nl & 63;
        *(bf16x8*)(oVt + ((size_t)((bb << 4) + h) * 64 + d) * 2048 + t0 + (c16 << 3)) = val;
      }
    }
  }
}

// ---------------- flash attention: swapped 32x32, KVBLK=128, FUSED dual-tile sweep ----------------
// grid = 512: bid = dp*64 + bh (bh fastest -> bh pinned to XCD bh%8).
// Block p owns q-tiles g1=p and g2=15-p; one kv sweep kt=0..g2 serves both.
// Dual iterations (kt<=g1) share kf fragments between both tiles' QK^T and run
// 8 independent MFMA chains before the softmax VALU phase (dep-break).
__global__ __launch_bounds__(256, 2) void flash_kernel(
    const u16b* __restrict__ Q, const u16b* __restrict__ K,
    const u16b* __restrict__ Vt, u16b* __restrict__ O) {
  __shared__ u16b smem[32768];  // 64KB: 2 buf x (K 16KB + V 16KB)
  const int bid = blockIdx.x;
  const int bh = bid & 63;
  const int dp = bid >> 6;
  const int p = (dp < 4) ? dp : (11 - dp);
  const int g1 = p, g2 = 15 - p;
  const int tid = threadIdx.x, wid = tid >> 6, lane = tid & 63;
  const int ln31 = lane & 31, hi = lane >> 5;
  const int l7 = ln31 & 7;
  const size_t baseQK = (size_t)bh * 2048 * 64;
  const size_t baseV = (size_t)bh * 64 * 2048;
  const int b = bh >> 4, h = bh & 15;
  const int rk = lane >> 3;
  const int sk = ((lane & 7) ^ rk) << 3;
  const int rv = lane >> 4;
  const int cv = lane & 15;

#define FSTAGE(kt, bi)                                                         \
  {                                                                            \
    char* kb_ = (char*)smem + (bi) * 32768;                                    \
    char* vb_ = kb_ + 16384;                                                   \
    const int k0_ = (kt) << 7;                                                 \
    _Pragma("unroll")                                                          \
    for (int c = 0; c < 4; ++c) {                                              \
      const int i = 4 * wid + c;                                               \
      const int r = 8 * i + rk;                                                \
      GLDS(K + baseQK + (size_t)(k0_ + r) * 64 + sk, kb_ + i * 1024);          \
    }                                                                          \
    _Pragma("unroll")                                                          \
    for (int c = 0; c < 4; ++c) {                                              \
      const int i = 4 * wid + c;                                               \
      const int r = 4 * i + rv;                                                \
      const int scv = (cv ^ (r & 7)) << 3;                                     \
      GLDS(Vt + baseV + (size_t)r * 2048 + k0_ + scv, vb_ + i * 1024);         \
    }                                                                          \
  }

  const int q0wA = (g1 << 7) + wid * 32;
  const int q0wB = (g2 << 7) + wid * 32;

  bf16x8 qfA[4], qfB[4];
  {
    const u16b* qpA = Q + baseQK + (size_t)(q0wA + ln31) * 64 + hi * 8;
    const u16b* qpB = Q + baseQK + (size_t)(q0wB + ln31) * 64 + hi * 8;
    #pragma unroll
    for (int kk = 0; kk < 4; ++kk) {
      qfA[kk] = *(const bf16x8*)(qpA + kk * 16);
      qfB[kk] = *(const bf16x8*)(qpB + kk * 16);
    }
  }

  float mA = -3e38f, lA = 0.f, mB = -3e38f, lB = 0.f;
  f32x16 oaA0 = {}, oaA1 = {}, oaB0 = {}, oaB1 = {};

  FSTAGE(0, 0);
  FSTAGE(1, 1);

  auto mask_diag = [&](f32x16* s) {
    #pragma unroll
    for (int ss = 0; ss < 4; ++ss) {
      if (ss == wid) {
        #pragma unroll
        for (int r = 0; r < 16; ++r) {
          const int kvr = (r & 3) + 8 * (r >> 2) + 4 * hi;
          if (kvr > ln31) s[ss][r] = -3e38f;
        }
      }
    }
  };

  auto softmax_tile = [&](f32x16* s, float& m_run, float& l_run,
                          f32x16& oa0, f32x16& oa1, const int maxsub) {
    float tm = -3e38f;
    #pragma unroll
    for (int ss = 0; ss < 4; ++ss)
      if (ss <= maxsub) tm = fmaxf(tm, max16(s[ss]));
    tm = fmaxf(tm, __shfl_xor(tm, 32));
    if (!__all(tm <= m_run + 8.f)) {
      const float mnew = fmaxf(m_run, tm);
      const float scale = __builtin_amdgcn_exp2f(m_run - mnew);
      m_run = mnew;
      l_run *= scale;
      #pragma unroll
      for (int r = 0; r < 16; ++r) { oa0[r] *= scale; oa1[r] *= scale; }
    }
    float rs = 0.f;
    #pragma unroll
    for (int ss = 0; ss < 4; ++ss) {
      if (ss <= maxsub) {
        #pragma unroll
        for (int r = 0; r < 16; ++r)
          s[ss][r] = __builtin_amdgcn_exp2f(s[ss][r] - m_run);
        rs += sum16(s[ss]);
      }
    }
    rs += __shfl_xor(rs, 32);
    l_run += rs;
  };

  auto pv_tile = [&](f32x16* s, f32x16& oa0, f32x16& oa1,
                     const int maxsub, const char* vb) {
    __builtin_amdgcn_s_setprio(1);
    #pragma unroll
    for (int ss = 0; ss < 4; ++ss) {
      if (ss <= maxsub) {
        const WB pa = packh<0>(s[ss]);
        const WB pb = packh<8>(s[ss]);
        const int cxa = ((4 * ss + hi) ^ l7) << 4;
        const int cxb = ((4 * ss + 2 + hi) ^ l7) << 4;
        const char* v0 = vb + ln31 * 256;
        const char* v1 = vb + (32 + ln31) * 256;
        oa0 = __builtin_amdgcn_mfma_f32_32x32x16_bf16(*(const bf16x8*)(v0 + cxa), pa.v, oa0, 0, 0, 0);
        oa1 = __builtin_amdgcn_mfma_f32_32x32x16_bf16(*(const bf16x8*)(v1 + cxa), pa.v, oa1, 0, 0, 0);
        oa0 = __builtin_amdgcn_mfma_f32_32x32x16_bf16(*(const bf16x8*)(v0 + cxb), pb.v, oa0, 0, 0, 0);
        oa1 = __builtin_amdgcn_mfma_f32_32x32x16_bf16(*(const bf16x8*)(v1 + cxb), pb.v, oa1, 0, 0, 0);
      }
    }
    __builtin_amdgcn_s_setprio(0);
  };

  #pragma unroll 1
  for (int kt = 0; kt <= g2; ++kt) {
    if (kt < g2) asm volatile("s_waitcnt vmcnt(8)" ::: "memory");
    else         asm volatile("s_waitcnt vmcnt(0)" ::: "memory");
    __builtin_amdgcn_s_barrier();

    const char* kb = (const char*)smem + (kt & 1) * 32768;
    const char* vb = kb + 16384;

    if (kt <= g1) {
      // ---- fused dual-tile iteration: shared kf, 8 independent QK chains ----
      const int maxA = (kt == g1) ? wid : 3;
      f32x16 sB[4] = {}, sA[4] = {};
      __builtin_amdgcn_s_setprio(1);
      #pragma unroll
      for (int ss = 0; ss < 4; ++ss) {
        const int row = 32 * ss + ln31;
        bf16x8 kf[4];
        #pragma unroll
        for (int kk = 0; kk < 4; ++kk)
          kf[kk] = *(const bf16x8*)(kb + row * 128 + (((2 * kk + hi) ^ l7) << 4));
        #pragma unroll
        for (int kk = 0; kk < 4; ++kk)
          sB[ss] = __builtin_amdgcn_mfma_f32_32x32x16_bf16(kf[kk], qfB[kk], sB[ss], 0, 0, 0);
        if (ss <= maxA) {
          #pragma unroll
          for (int kk = 0; kk < 4; ++kk)
            sA[ss] = __builtin_amdgcn_mfma_f32_32x32x16_bf16(kf[kk], qfA[kk], sA[ss], 0, 0, 0);
        }
      }
      __builtin_amdgcn_s_setprio(0);

      if (kt == g1) mask_diag(sA);
      softmax_tile(sB, mB, lB, oaB0, oaB1, 3);
      softmax_tile(sA, mA, lA, oaA0, oaA1, maxA);
      pv_tile(sB, oaB0, oaB1, 3, vb);
      pv_tile(sA, oaA0, oaA1, maxA, vb);
    } else {
      // ---- single-tile iteration (B only) ----
      const int maxB = (kt == g2) ? wid : 3;
      f32x16 sB[4] = {};
      __builtin_amdgcn_s_setprio(1);
      #pragma unroll
      for (int ss = 0; ss < 4; ++ss) {
        if (ss <= maxB) {
          const int row = 32 * ss + ln31;
          #pragma unroll
          for (int kk = 0; kk < 4; ++kk) {
            const bf16x8 kf = *(const bf16x8*)(kb + row * 128 + (((2 * kk + hi) ^ l7) << 4));
            sB[ss] = __builtin_amdgcn_mfma_f32_32x32x16_bf16(kf, qfB[kk], sB[ss], 0, 0, 0);
          }
        }
      }
      __builtin_amdgcn_s_setprio(0);

      if (kt == g2) mask_diag(sB);
      softmax_tile(sB, mB, lB, oaB0, oaB1, maxB);
      pv_tile(sB, oaB0, oaB1, maxB, vb);
    }

    __builtin_amdgcn_s_barrier();
    if (kt + 2 <= g2) FSTAGE(kt + 2, kt & 1);
  }

  // ---- epilogues ----
  {
    const float inv = 1.0f / lA;
    const int q = q0wA + ln31;
    u16b* orow = O + (size_t)(b * 2048 + q) * 1024 + h * 64;
    #pragma unroll
    for (int rq = 0; rq < 4; ++rq) {
      u16x4 v0, v1;
      #pragma unroll
      for (int j = 0; j < 4; ++j) {
        v0[j] = bfr(oaA0[4 * rq + j] * inv);
        v1[j] = bfr(oaA1[4 * rq + j] * inv);
      }
      const int d0 = 8 * rq + 4 * hi;
      *(u16x4*)(orow + d0) = v0;
      *(u16x4*)(orow + 32 + d0) = v1;
    }
  }
  {
    const float inv = 1.0f / lB;
    const int q = q0wB + ln31;
    u16b* orow = O + (size_t)(b * 2048 + q) * 1024 + h * 64;
    #pragma unroll
    for (int rq = 0; rq < 4; ++rq) {
      u16x4 v0, v1;
      #pragma unroll
      for (int j = 0; j < 4; ++j) {
        v0[j] = bfr(oaB0[4 * rq + j] * inv);
        v1[j] = bfr(oaB1[4 * rq + j] * inv);
      }
      const int d0 = 8 * rq + 4 * hi;
      *(u16x4*)(orow + d0) = v0;
      *(u16x4*)(orow + 32 + d0) = v1;
    }
  }
#undef FSTAGE
}

extern "C" void kernel_launch(void* const* d_in, const int* in_sizes, int n_in,
                              void* d_out, int out_size, void* d_ws, size_t ws_size,
                              hipStream_t stream) {
  const float* x      = (const float*)d_in[0];
  const float* w_attn = (const float*)d_in[1];
  const float* b_attn = (const float*)d_in[2];
  const float* w_proj = (const float*)d_in[3];
  const float* b_proj = (const float*)d_in[4];
  float* out = (float*)d_out;
  char* ws = (char*)d_ws;

  u16b* xb  = (u16b*)(ws + 0);          // [8192][1024] bf16 x; later reused as attn_out
  u16b* waT = (u16b*)(ws + 16777216);   // [3072][1024] w_attn^T bf16
  u16b* wpT = (u16b*)(ws + 23068672);   // [1024][1024] w_proj^T bf16
  u16b* Qb  = (u16b*)(ws + 25165824);   // [64 bh][2048][64]
  u16b* Kb  = (u16b*)(ws + 41943040);
  u16b* Vtb = (u16b*)(ws + 75497472);   // [64 bh][64][2048] (written directly by qkv GEMM)
  u16b* attn = xb;

  cvt_bf16_kernel<<<2048, 256, 0, stream>>>(x, xb, (8192 * 1024) / 4);
  transpose_cvt_kernel<<<16 * 48, 256, 0, stream>>>(w_attn, waT, 1024, 3072);
  transpose_cvt_kernel<<<16 * 16, 256, 0, stream>>>(w_proj, wpT, 1024, 1024);
  gemm128_kernel<0><<<64 * 24, 256, 0, stream>>>(xb, waT, b_attn, Qb, Kb, Vtb, nullptr,
                                                 8192, 3072, 1024);
  flash_kernel<<<512, 256, 0, stream>>>(Qb, Kb, Vtb, attn);
  gemm128_kernel<1><<<64 * 8, 256, 0, stream>>>(attn, wpT, b_proj, nullptr, nullptr, nullptr,
                                                out, 8192, 1024, 1024);
}

// Round 8
// 171.973 us; speedup vs baseline: 1.7599x; 1.7599x over previous
//
#include <hip/hip_runtime.h>

// CausalSelfAttention: B=4, T=2048, C=1024, H=16, D=64
// Pipeline: cvt(x,w) -> qkv GEMM (dbuf, XCD-chunked, T2-swizzled LDS, V written transposed)
//           -> flash attn (swapped 32x32, KVBLK=128, merged dual-q-tile sweep SEQUENTIAL,
//              defer-max, dbuf)  [round-6 structure; round-7 fusion spilled to scratch]
//           -> proj GEMM

typedef unsigned short u16b;
typedef __bf16 bf16x8 __attribute__((ext_vector_type(8)));
typedef float f32x4 __attribute__((ext_vector_type(4)));
typedef float f32x16 __attribute__((ext_vector_type(16)));
typedef unsigned short u16x4 __attribute__((ext_vector_type(4)));

#define AS1(p) ((const __attribute__((address_space(1))) void*)(p))
#define AS3(p) ((__attribute__((address_space(3))) void*)(p))
#define GLDS(g, l) __builtin_amdgcn_global_load_lds(AS1(g), AS3(l), 16, 0, 0)

__device__ __forceinline__ u16b bfr(float v) {  // f32 -> bf16 bits, RNE
  union { float f; unsigned u; } x; x.f = v;
  unsigned r = x.u + 0x7fffu + ((x.u >> 16) & 1u);
  return (u16b)(r >> 16);
}

__device__ __forceinline__ unsigned pk2(float lo, float hi) {  // pack 2 f32 -> 2 bf16 in u32
  union { __bf16 h[2]; unsigned u; } t;
  t.h[0] = (__bf16)lo; t.h[1] = (__bf16)hi;
  return t.u;
}

__device__ __forceinline__ float max16(const f32x16& v) {
  float a0 = fmaxf(v[0], v[1]), a1 = fmaxf(v[2], v[3]);
  float a2 = fmaxf(v[4], v[5]), a3 = fmaxf(v[6], v[7]);
  float b0 = fmaxf(v[8], v[9]), b1 = fmaxf(v[10], v[11]);
  float b2 = fmaxf(v[12], v[13]), b3 = fmaxf(v[14], v[15]);
  float c0 = fmaxf(a0, a1), c1 = fmaxf(a2, a3);
  float c2 = fmaxf(b0, b1), c3 = fmaxf(b2, b3);
  return fmaxf(fmaxf(c0, c1), fmaxf(c2, c3));
}

__device__ __forceinline__ float sum16(const f32x16& v) {
  float a0 = v[0] + v[1], a1 = v[2] + v[3], a2 = v[4] + v[5], a3 = v[6] + v[7];
  float b0 = v[8] + v[9], b1 = v[10] + v[11], b2 = v[12] + v[13], b3 = v[14] + v[15];
  float c0 = a0 + a1, c1 = a2 + a3, c2 = b0 + b1, c3 = b2 + b3;
  return (c0 + c1) + (c2 + c3);
}

// ---------------- x (fp32) -> bf16, vectorized ----------------
__global__ __launch_bounds__(256) void cvt_bf16_kernel(
    const float* __restrict__ src, u16b* __restrict__ dst, int n4) {
  int i = blockIdx.x * 256 + threadIdx.x;
  const int stride = gridDim.x * 256;
  for (; i < n4; i += stride) {
    const float4 v = reinterpret_cast<const float4*>(src)[i];
    u16x4 o;
    o[0] = bfr(v.x); o[1] = bfr(v.y); o[2] = bfr(v.z); o[3] = bfr(v.w);
    reinterpret_cast<u16x4*>(dst)[i] = o;
  }
}

// ---------------- weights: src[R][C] fp32 -> dst[C][R] bf16 (transpose) ----------------
__global__ __launch_bounds__(256) void transpose_cvt_kernel(
    const float* __restrict__ src, u16b* __restrict__ dst, int R, int C) {
  __shared__ u16b tile[64][72];
  const int nc = C >> 6;
  const int br = blockIdx.x / nc, bc = blockIdx.x % nc;
  const int r0 = br << 6, c0 = bc << 6;
  const int c = threadIdx.x & 63, r4 = threadIdx.x >> 6;
  #pragma unroll
  for (int i = 0; i < 16; ++i) {
    const int r = r4 + 4 * i;
    tile[r][c] = bfr(src[(size_t)(r0 + r) * C + c0 + c]);
  }
  __syncthreads();
  #pragma unroll
  for (int i = 0; i < 16; ++i) {
    const int rr = r4 + 4 * i;
    dst[(size_t)(c0 + rr) * R + r0 + c] = tile[c][rr];
  }
}

// ---------------- 128x128 tile bf16 GEMM: dbuf + XCD chunking + T2 swizzle ----------------
// LDS A/B tiles: [128 rows][64 B], physical 16B-chunk = logical ^ ((row>>1)&3).
// Staged with linear GLDS dest + pre-swizzled SOURCE chunk (rule #21).
// EPI==0: Q(scaled)/K as [B,H,T,D] bf16; V written TRANSPOSED as Vt [bh][64 d][2048 t]
// EPI==1: fp32 out [M][N]
template <int EPI>
__global__ __launch_bounds__(256, 2) void gemm128_kernel(
    const u16b* __restrict__ A, const u16b* __restrict__ Bt,
    const float* __restrict__ bias,
    u16b* __restrict__ oQ, u16b* __restrict__ oK, u16b* __restrict__ oVt,
    float* __restrict__ oF, int M, int N, int K) {
  __shared__ u16b smem[16384];  // 2 buf x (As 8KB + Bs 8KB); epilogue reuses all 32KB
  const int tid = threadIdx.x;
  const int wid = tid >> 6, lane = tid & 63;
  const int nb = N >> 7;
  const int lin = (blockIdx.x & 7) * ((int)gridDim.x >> 3) + (blockIdx.x >> 3);
  const int brow = lin / nb, bcol = lin % nb;
  const int wr = (wid >> 1) << 6, wc = (wid & 1) << 6;

  f32x4 acc[4][4] = {};

  const int ar = (wid << 4) + (lane >> 2);
  // source chunk pre-swizzle: row = ar, row>>1 bits = (lane>>3)&3
  const int acs = (((lane & 3) ^ ((lane >> 3) & 3))) << 3;
  const u16b* Ab = A + (size_t)((brow << 7) + ar) * K + acs;
  const u16b* Bb = Bt + (size_t)((bcol << 7) + ar) * K + acs;
  const int fr = lane & 15;
  const int pcs = (((lane >> 4) ^ ((fr >> 1) & 3))) << 4;  // phys chunk byte off for reads
  const int nk = K >> 5;

#define STAGE(bufi, kk)                                                        \
  {                                                                            \
    char* sb = (char*)smem + (bufi) * 16384;                                   \
    GLDS(Ab + (kk),                  sb + wid * 1024);                         \
    GLDS(Ab + (size_t)64 * K + (kk), sb + 4096 + wid * 1024);                  \
    GLDS(Bb + (kk),                  sb + 8192 + wid * 1024);                  \
    GLDS(Bb + (size_t)64 * K + (kk), sb + 12288 + wid * 1024);                 \
  }

  STAGE(0, 0);
  STAGE(1, 32);

  #pragma unroll 1
  for (int kt = 0; kt < nk; ++kt) {
    if (kt + 1 < nk) asm volatile("s_waitcnt vmcnt(4)" ::: "memory");
    else             asm volatile("s_waitcnt vmcnt(0)" ::: "memory");
    __builtin_amdgcn_s_barrier();

    const char* As = (const char*)smem + (kt & 1) * 16384;
    const char* Bs = As + 8192;
    bf16x8 af[4], bfv[4];
    #pragma unroll
    for (int i = 0; i < 4; ++i)
      af[i] = *(const bf16x8*)(As + (wr + i * 16 + fr) * 64 + pcs);
    #pragma unroll
    for (int j = 0; j < 4; ++j)
      bfv[j] = *(const bf16x8*)(Bs + (wc + j * 16 + fr) * 64 + pcs);
    __builtin_amdgcn_s_setprio(1);
    #pragma unroll
    for (int i = 0; i < 4; ++i)
      #pragma unroll
      for (int j = 0; j < 4; ++j)
        acc[i][j] = __builtin_amdgcn_mfma_f32_16x16x32_bf16(af[i], bfv[j], acc[i][j], 0, 0, 0);
    __builtin_amdgcn_s_setprio(0);

    __builtin_amdgcn_s_barrier();
    if (kt + 2 < nk) STAGE(kt & 1, (kt + 2) << 5);
  }
#undef STAGE

  const int fq = lane >> 4;
  if (EPI == 1) {
    #pragma unroll
    for (int j = 0; j < 4; ++j) {
      const int n0 = (bcol << 7) + wc + j * 16 + fr;
      const float bv = bias[n0];
      #pragma unroll
      for (int i = 0; i < 4; ++i) {
        #pragma unroll
        for (int r = 0; r < 4; ++r) {
          const int m0 = (brow << 7) + wr + i * 16 + fq * 4 + r;
          oF[(size_t)m0 * N + n0] = acc[i][j][r] + bv;
        }
      }
    }
  } else {
    const int sect = bcol >> 3;  // 0:Q 1:K 2:V (block-uniform)
    if (sect < 2) {
      const float qs = (sect == 0) ? 0.1803368801f : 1.0f;  // 1/sqrt(64)*log2(e) in Q
      u16b* oPtr = (sect == 0) ? oQ : oK;
      u16b* tile = (u16b*)smem;
      #pragma unroll
      for (int j = 0; j < 4; ++j) {
        const int n = wc + j * 16 + fr;
        const float bv = bias[(bcol << 7) + n];
        #pragma unroll
        for (int i = 0; i < 4; ++i) {
          #pragma unroll
          for (int r = 0; r < 4; ++r) {
            const int m = wr + i * 16 + fq * 4 + r;
            const int byteoff = m * 256 + (((n >> 3) ^ (m & 7)) << 4) + ((n & 7) << 1);
            *(u16b*)((char*)tile + byteoff) = bfr((acc[i][j][r] + bv) * qs);
          }
        }
      }
      __syncthreads();
      const int nh = wid >> 1;
      const int c = lane & 7;
      #pragma unroll
      for (int it = 0; it < 8; ++it) {
        const int m = ((wid & 1) << 6) + (it << 3) + (lane >> 3);
        const int chunk = (nh << 3) + (c ^ (m & 7));
        const bf16x8 val = *(const bf16x8*)((const char*)tile + m * 256 + chunk * 16);
        const int m0 = (brow << 7) + m;
        const int n0 = (bcol << 7) + (nh << 6) + (c << 3);
        const int bb = m0 >> 11, tt = m0 & 2047;
        const int h = (n0 >> 6) & 15, d = n0 & 63;
        *(bf16x8*)(oPtr + (((size_t)(bb * 16 + h) * 2048 + tt) * 64 + d)) = val;
      }
    } else {
      // V: LDS tile TRANSPOSED [nl 128][m 128] swizzled, store Vt[bh][d][t] rows
      u16b* tile = (u16b*)smem;
      #pragma unroll
      for (int j = 0; j < 4; ++j) {
        const int nl = wc + j * 16 + fr;
        const float bv = bias[(bcol << 7) + nl];
        #pragma unroll
        for (int i = 0; i < 4; ++i) {
          #pragma unroll
          for (int r = 0; r < 4; ++r) {
            const int m = wr + i * 16 + fq * 4 + r;
            const int byteoff = nl * 256 + (((m >> 3) ^ (nl & 7)) << 4) + ((m & 7) << 1);
            *(u16b*)((char*)tile + byteoff) = bfr(acc[i][j][r] + bv);
          }
        }
      }
      __syncthreads();
      const int row0 = wid << 5;
      const int c16 = lane & 15;
      const int rr = lane >> 4;
      const int t0 = (brow << 7) & 2047;
      const int bb = brow >> 4;
      #pragma unroll
      for (int it = 0; it < 8; ++it) {
        const int nl = row0 + (it << 2) + rr;
        const int pch = c16 ^ (nl & 7);
        const bf16x8 val = *(const bf16x8*)((const char*)tile + nl * 256 + pch * 16);
        const int h = ((bcol & 7) << 1) + (nl >> 6);
        const int d = nl & 63;
        *(bf16x8*)(oVt + ((size_t)((bb << 4) + h) * 64 + d) * 2048 + t0 + (c16 << 3)) = val;
      }
    }
  }
}

// ---------------- flash attention: swapped 32x32, KVBLK=128, merged dual-tile sweep ----------------
// Round-6 structure: SEQUENTIAL per-tile compute (one S-tile live at a time — the
// round-7 fusion held two and spilled to scratch, 3x regression).
__global__ __launch_bounds__(256, 2) void flash_kernel(
    const u16b* __restrict__ Q, const u16b* __restrict__ K,
    const u16b* __restrict__ Vt, u16b* __restrict__ O) {
  __shared__ u16b smem[32768];  // 64KB
  const int bid = blockIdx.x;
  const int bh = bid & 63;
  const int dp = bid >> 6;                    // dispatch slot 0..7
  const int p = (dp < 4) ? dp : (11 - dp);    // pair (0,7),(1,6),(2,5),(3,4)
  const int g1 = p, g2 = 15 - p;
  const int tid = threadIdx.x, wid = tid >> 6, lane = tid & 63;
  const int ln31 = lane & 31, hi = lane >> 5;
  const int l7 = ln31 & 7;
  const size_t baseQK = (size_t)bh * 2048 * 64;
  const size_t baseV = (size_t)bh * 64 * 2048;
  const int b = bh >> 4, h = bh & 15;
  const int rk = lane >> 3;
  const int sk = ((lane & 7) ^ rk) << 3;
  const int rv = lane >> 4;
  const int cv = lane & 15;

#define FSTAGE(kt, bi)                                                         \
  {                                                                            \
    char* kb_ = (char*)smem + (bi) * 32768;                                    \
    char* vb_ = kb_ + 16384;                                                   \
    const int k0_ = (kt) << 7;                                                 \
    _Pragma("unroll")                                                          \
    for (int c = 0; c < 4; ++c) {                                              \
      const int i = 4 * wid + c;                                               \
      const int r = 8 * i + rk;                                                \
      GLDS(K + baseQK + (size_t)(k0_ + r) * 64 + sk, kb_ + i * 1024);          \
    }                                                                          \
    _Pragma("unroll")                                                          \
    for (int c = 0; c < 4; ++c) {                                              \
      const int i = 4 * wid + c;                                               \
      const int r = 4 * i + rv;                                                \
      const int scv = (cv ^ (r & 7)) << 3;                                     \
      GLDS(Vt + baseV + (size_t)r * 2048 + k0_ + scv, vb_ + i * 1024);         \
    }                                                                          \
  }

  const int q0wA = (g1 << 7) + wid * 32;
  const int q0wB = (g2 << 7) + wid * 32;

  bf16x8 qfA[4], qfB[4];
  {
    const u16b* qpA = Q + baseQK + (size_t)(q0wA + ln31) * 64 + hi * 8;
    const u16b* qpB = Q + baseQK + (size_t)(q0wB + ln31) * 64 + hi * 8;
    #pragma unroll
    for (int kk = 0; kk < 4; ++kk) {
      qfA[kk] = *(const bf16x8*)(qpA + kk * 16);
      qfB[kk] = *(const bf16x8*)(qpB + kk * 16);
    }
  }

  float mA = -3e38f, lA = 0.f, mB = -3e38f, lB = 0.f;
  f32x16 oaA0 = {}, oaA1 = {}, oaB0 = {}, oaB1 = {};

  FSTAGE(0, 0);
  FSTAGE(1, 1);

  #pragma unroll 1
  for (int kt = 0; kt <= g2; ++kt) {
    if (kt < g2) asm volatile("s_waitcnt vmcnt(8)" ::: "memory");
    else         asm volatile("s_waitcnt vmcnt(0)" ::: "memory");
    __builtin_amdgcn_s_barrier();

    const char* kb = (const char*)smem + (kt & 1) * 32768;
    const char* vb = kb + 16384;

    auto compute_tile = [&](const bf16x8* qf, float& m_run, float& l_run,
                            f32x16& oa0, f32x16& oa1, const int gq) {
      const bool diag = (kt == gq);
      const int maxsub = diag ? wid : 3;  // wave-uniform

      f32x16 s[4] = {};
      __builtin_amdgcn_s_setprio(1);
      #pragma unroll
      for (int ss = 0; ss < 4; ++ss) {
        if (ss <= maxsub) {
          const int row = 32 * ss + ln31;
          #pragma unroll
          for (int kk = 0; kk < 4; ++kk) {
            const int ch = (2 * kk + hi) ^ l7;
            const bf16x8 kf = *(const bf16x8*)(kb + row * 128 + ch * 16);
            s[ss] = __builtin_amdgcn_mfma_f32_32x32x16_bf16(kf, qf[kk], s[ss], 0, 0, 0);
          }
        }
      }
      __builtin_amdgcn_s_setprio(0);

      if (diag) {
        #pragma unroll
        for (int ss = 0; ss < 4; ++ss) {
          if (ss == wid) {
            #pragma unroll
            for (int r = 0; r < 16; ++r) {
              const int kvr = (r & 3) + 8 * (r >> 2) + 4 * hi;
              if (kvr > ln31) s[ss][r] = -3e38f;
            }
          }
        }
      }

      float tm = -3e38f;
      #pragma unroll
      for (int ss = 0; ss < 4; ++ss)
        if (ss <= maxsub) tm = fmaxf(tm, max16(s[ss]));
      tm = fmaxf(tm, __shfl_xor(tm, 32));

      if (!__all(tm <= m_run + 8.f)) {
        const float mnew = fmaxf(m_run, tm);
        const float scale = __builtin_amdgcn_exp2f(m_run - mnew);
        m_run = mnew;
        l_run *= scale;
        #pragma unroll
        for (int r = 0; r < 16; ++r) { oa0[r] *= scale; oa1[r] *= scale; }
      }

      float rs = 0.f;
      #pragma unroll
      for (int ss = 0; ss < 4; ++ss) {
        if (ss <= maxsub) {
          #pragma unroll
          for (int r = 0; r < 16; ++r)
            s[ss][r] = __builtin_amdgcn_exp2f(s[ss][r] - m_run);
          rs += sum16(s[ss]);
        }
      }
      rs += __shfl_xor(rs, 32);
      l_run += rs;

      union WB { unsigned u[4]; bf16x8 v; };
      __builtin_amdgcn_s_setprio(1);
      #pragma unroll
      for (int ss = 0; ss < 4; ++ss) {
        if (ss <= maxsub) {
          WB pA, pB;
#define MKPA(W0, W1, W2, W3, P0, P1, P2, P3, P4, P5, P6, P7)                 \
          {                                                                   \
            unsigned a0 = pk2(P0, P1), a1 = pk2(P2, P3);                      \
            unsigned b0 = pk2(P4, P5), b1 = pk2(P6, P7);                      \
            auto r0 = __builtin_amdgcn_permlane32_swap(a0, b0, false, false); \
            auto r1 = __builtin_amdgcn_permlane32_swap(a1, b1, false, false); \
            unsigned o0[2], o1[2];                                            \
            __builtin_memcpy(o0, &r0, 8); __builtin_memcpy(o1, &r1, 8);       \
            W0 = o0[0]; W2 = o0[1]; W1 = o1[0]; W3 = o1[1];                   \
          }
          MKPA(pA.u[0], pA.u[1], pA.u[2], pA.u[3],
               s[ss][0], s[ss][1], s[ss][2], s[ss][3],
               s[ss][4], s[ss][5], s[ss][6], s[ss][7]);
          MKPA(pB.u[0], pB.u[1], pB.u[2], pB.u[3],
               s[ss][8], s[ss][9], s[ss][10], s[ss][11],
               s[ss][12], s[ss][13], s[ss][14], s[ss][15]);
#undef MKPA
          const int cxa = ((4 * ss + hi) ^ l7) << 4;
          const int cxb = ((4 * ss + 2 + hi) ^ l7) << 4;
          const char* v0 = vb + ln31 * 256;
          const char* v1 = vb + (32 + ln31) * 256;
          oa0 = __builtin_amdgcn_mfma_f32_32x32x16_bf16(*(const bf16x8*)(v0 + cxa), pA.v, oa0, 0, 0, 0);
          oa1 = __builtin_amdgcn_mfma_f32_32x32x16_bf16(*(const bf16x8*)(v1 + cxa), pA.v, oa1, 0, 0, 0);
          oa0 = __builtin_amdgcn_mfma_f32_32x32x16_bf16(*(const bf16x8*)(v0 + cxb), pB.v, oa0, 0, 0, 0);
          oa1 = __builtin_amdgcn_mfma_f32_32x32x16_bf16(*(const bf16x8*)(v1 + cxb), pB.v, oa1, 0, 0, 0);
        }
      }
      __builtin_amdgcn_s_setprio(0);
    };

    compute_tile(qfB, mB, lB, oaB0, oaB1, g2);
    if (kt <= g1) compute_tile(qfA, mA, lA, oaA0, oaA1, g1);

    __builtin_amdgcn_s_barrier();
    if (kt + 2 <= g2) FSTAGE(kt + 2, kt & 1);
  }

  // ---- epilogues: lane owns output rows q0w{A,B}+ln31 ----
  {
    const float inv = 1.0f / lA;
    const int q = q0wA + ln31;
    u16b* orow = O + (size_t)(b * 2048 + q) * 1024 + h * 64;
    #pragma unroll
    for (int rq = 0; rq < 4; ++rq) {
      u16x4 v0, v1;
      #pragma unroll
      for (int j = 0; j < 4; ++j) {
        v0[j] = bfr(oaA0[4 * rq + j] * inv);
        v1[j] = bfr(oaA1[4 * rq + j] * inv);
      }
      const int d0 = 8 * rq + 4 * hi;
      *(u16x4*)(orow + d0) = v0;
      *(u16x4*)(orow + 32 + d0) = v1;
    }
  }
  {
    const float inv = 1.0f / lB;
    const int q = q0wB + ln31;
    u16b* orow = O + (size_t)(b * 2048 + q) * 1024 + h * 64;
    #pragma unroll
    for (int rq = 0; rq < 4; ++rq) {
      u16x4 v0, v1;
      #pragma unroll
      for (int j = 0; j < 4; ++j) {
        v0[j] = bfr(oaB0[4 * rq + j] * inv);
        v1[j] = bfr(oaB1[4 * rq + j] * inv);
      }
      const int d0 = 8 * rq + 4 * hi;
      *(u16x4*)(orow + d0) = v0;
      *(u16x4*)(orow + 32 + d0) = v1;
    }
  }
#undef FSTAGE
}

extern "C" void kernel_launch(void* const* d_in, const int* in_sizes, int n_in,
                              void* d_out, int out_size, void* d_ws, size_t ws_size,
                              hipStream_t stream) {
  const float* x      = (const float*)d_in[0];
  const float* w_attn = (const float*)d_in[1];
  const float* b_attn = (const float*)d_in[2];
  const float* w_proj = (const float*)d_in[3];
  const float* b_proj = (const float*)d_in[4];
  float* out = (float*)d_out;
  char* ws = (char*)d_ws;

  u16b* xb  = (u16b*)(ws + 0);          // [8192][1024] bf16 x; later reused as attn_out
  u16b* waT = (u16b*)(ws + 16777216);   // [3072][1024] w_attn^T bf16
  u16b* wpT = (u16b*)(ws + 23068672);   // [1024][1024] w_proj^T bf16
  u16b* Qb  = (u16b*)(ws + 25165824);   // [64 bh][2048][64]
  u16b* Kb  = (u16b*)(ws + 41943040);
  u16b* Vtb = (u16b*)(ws + 75497472);   // [64 bh][64][2048] (written directly by qkv GEMM)
  u16b* attn = xb;

  cvt_bf16_kernel<<<2048, 256, 0, stream>>>(x, xb, (8192 * 1024) / 4);
  transpose_cvt_kernel<<<16 * 48, 256, 0, stream>>>(w_attn, waT, 1024, 3072);
  transpose_cvt_kernel<<<16 * 16, 256, 0, stream>>>(w_proj, wpT, 1024, 1024);
  gemm128_kernel<0><<<64 * 24, 256, 0, stream>>>(xb, waT, b_attn, Qb, Kb, Vtb, nullptr,
                                                 8192, 3072, 1024);
  flash_kernel<<<512, 256, 0, stream>>>(Qb, Kb, Vtb, attn);
  gemm128_kernel<1><<<64 * 8, 256, 0, stream>>>(attn, wpT, b_proj, nullptr, nullptr, nullptr,
                                                out, 8192, 1024, 1024);
}